// Round 7
// baseline (419.950 us; speedup 1.0000x reference)
//
#include <hip/hip_runtime.h>

#define N_NODES 100000
#define EDGES   1600000
#define CH      128
#define BN_EPS  1e-5f

#define BINS     782                  // ceil(100000 / 128)
#define CHUNKS   128                  // edge chunks for binning
#define CHUNK_E  (EDGES / CHUNKS)     // 12500, exact
#define HM       (BINS * CHUNKS)      // 100096 histogram cells
#define SCAN_NB  (HM / 256)           // 391, exact
#define NREP     64                   // BN-partial replicas

typedef __attribute__((ext_vector_type(8))) __bf16 bf16x8;
typedef __attribute__((ext_vector_type(4))) __bf16 bf16x4;
typedef __attribute__((ext_vector_type(2))) __bf16 bf16x2;
typedef __attribute__((ext_vector_type(4))) float  f32x4;

// ---------------------------------------------------------------------------
// Pass 1: per-(bin, chunk) histogram.  histo_g[bin*CHUNKS + chunk]
// ---------------------------------------------------------------------------
__global__ __launch_bounds__(256) void histo_kernel(const int* __restrict__ dst,
                                                    int* __restrict__ histo_g) {
    __shared__ int h[BINS];
    int t = threadIdx.x;
    for (int b = t; b < BINS; b += 256) h[b] = 0;
    __syncthreads();
    int base = blockIdx.x * CHUNK_E;
    for (int i = t; i < CHUNK_E; i += 256)
        atomicAdd(&h[dst[base + i] >> 7], 1);
    __syncthreads();
    for (int b = t; b < BINS; b += 256)
        histo_g[b * CHUNKS + blockIdx.x] = h[b];
}

// ---------------------------------------------------------------------------
// exclusive scan over HM elements
// ---------------------------------------------------------------------------
__global__ __launch_bounds__(256) void scan1(const int* __restrict__ in,
                                             int* __restrict__ scanned,
                                             int* __restrict__ blocksum) {
    __shared__ int sh[2][256];
    int t = threadIdx.x;
    int i = blockIdx.x * 256 + t;
    int v = in[i];
    sh[0][t] = v;
    __syncthreads();
    int pp = 0;
    #pragma unroll
    for (int off = 1; off < 256; off <<= 1) {
        int val = sh[pp][t] + ((t >= off) ? sh[pp][t - off] : 0);
        sh[1 - pp][t] = val;
        pp = 1 - pp;
        __syncthreads();
    }
    int incl = sh[pp][t];
    scanned[i] = incl - v;
    if (t == 255) blocksum[blockIdx.x] = incl;
}

__global__ __launch_bounds__(512) void scan2(int* __restrict__ blocksum) {
    __shared__ int sh[2][512];
    int t = threadIdx.x;
    int v = (t < SCAN_NB) ? blocksum[t] : 0;
    sh[0][t] = v;
    __syncthreads();
    int pp = 0;
    #pragma unroll
    for (int off = 1; off < 512; off <<= 1) {
        int val = sh[pp][t] + ((t >= off) ? sh[pp][t - off] : 0);
        sh[1 - pp][t] = val;
        pp = 1 - pp;
        __syncthreads();
    }
    if (t < SCAN_NB) blocksum[t] = sh[pp][t] - v;
}

__global__ __launch_bounds__(256) void scan3(int* __restrict__ scanned,
                                             const int* __restrict__ blocksum) {
    int i = blockIdx.x * 256 + threadIdx.x;
    scanned[i] += blocksum[blockIdx.x];
    if (i == HM - 1) scanned[HM] = EDGES;
}

// ---------------------------------------------------------------------------
// Pass 2: placement.  binned[pos] = (src << 7) | (dst & 127)
// ---------------------------------------------------------------------------
__global__ __launch_bounds__(256) void place_kernel(const int* __restrict__ src,
                                                    const int* __restrict__ dst,
                                                    const int* __restrict__ scanned,
                                                    int* __restrict__ binned) {
    __shared__ int cur[BINS];
    int t = threadIdx.x;
    for (int b = t; b < BINS; b += 256)
        cur[b] = scanned[b * CHUNKS + blockIdx.x];
    __syncthreads();
    int base = blockIdx.x * CHUNK_E;
    for (int i = t; i < CHUNK_E; i += 256) {
        int d = dst[base + i];
        int s = src[base + i];
        int pos = atomicAdd(&cur[d >> 7], 1);
        binned[pos] = (s << 7) | (d & 127);
    }
}

// ---------------------------------------------------------------------------
// Pass 3: per-bin counting sort -> full CSR (srcs sorted by dst), rowptr, dinv.
// ---------------------------------------------------------------------------
__global__ __launch_bounds__(256) void bin_csr(const int* __restrict__ binned,
                                               const int* __restrict__ scanned,
                                               int* __restrict__ srcs,
                                               int* __restrict__ rowptr,
                                               float* __restrict__ dinv) {
    __shared__ int cnt[128];
    __shared__ int sc[2][128];
    __shared__ int base[128];
    __shared__ int cur[128];
    const int t = threadIdx.x;
    const int bin = blockIdx.x;
    if (t < 128) { cnt[t] = 0; cur[t] = 0; }
    __syncthreads();
    const int beg = scanned[bin * CHUNKS];
    const int end = scanned[bin * CHUNKS + CHUNKS];
    for (int e = beg + t; e < end; e += 256)
        atomicAdd(&cnt[binned[e] & 127], 1);
    __syncthreads();
    if (t < 128) sc[0][t] = cnt[t];
    __syncthreads();
    int pp = 0;
    #pragma unroll
    for (int off = 1; off < 128; off <<= 1) {
        if (t < 128) sc[1 - pp][t] = sc[pp][t] + ((t >= off) ? sc[pp][t - off] : 0);
        pp = 1 - pp;
        __syncthreads();
    }
    if (t < 128) {
        base[t] = beg + sc[pp][t] - cnt[t];
        int n = (bin << 7) + t;
        if (n < N_NODES) {
            rowptr[n] = base[t];
            dinv[n] = rsqrtf((float)cnt[t] + 1.0f);
        }
    }
    if (bin == 0 && t == 0) rowptr[N_NODES] = EDGES;
    __syncthreads();
    for (int e = beg + t; e < end; e += 256) {
        int p = binned[e];
        int dl = p & 127;
        int pos = base[dl] + atomicAdd(&cur[dl], 1);
        srcs[pos] = p >> 7;
    }
}

// ---------------------------------------------------------------------------
// W transpose + bf16 convert for BOTH weights: Wt[n][k] = bf16(W[k][n])
// ---------------------------------------------------------------------------
__global__ __launch_bounds__(256) void wtrans2(const float* __restrict__ W1,
                                               __bf16* __restrict__ Wt1,
                                               const float* __restrict__ W2,
                                               __bf16* __restrict__ Wt2) {
    int b = blockIdx.x;
    const float* W = (b < 64) ? W1 : W2;
    __bf16* Wt = (b < 64) ? Wt1 : Wt2;
    int idx = (b & 63) * 256 + threadIdx.x;
    int n = idx >> 7, k = idx & 127;
    Wt[idx] = (__bf16)W[k * 128 + n];
}

// ---------------------------------------------------------------------------
// conv1 GEMM (fp32 A): hs[n][c] = bf16( dinv[n] * sum_k A[n][k] * W[k][c] )
// ---------------------------------------------------------------------------
__global__ __launch_bounds__(256) void gemm_f32(const float* __restrict__ A,
                                                const __bf16* __restrict__ Wt,
                                                const float* __restrict__ dinv,
                                                __bf16* __restrict__ hs) {
    const int wave = threadIdx.x >> 6;
    const int rt = blockIdx.x * 4 + wave;
    if (rt >= N_NODES / 16) return;
    const int lane = threadIdx.x & 63;
    const int ln = lane & 15;
    const int quad = lane >> 4;
    const int arow = rt * 16 + ln;

    f32x4 acc[8];
    #pragma unroll
    for (int ct = 0; ct < 8; ++ct) acc[ct] = (f32x4){0.f, 0.f, 0.f, 0.f};

    #pragma unroll
    for (int k0 = 0; k0 < 128; k0 += 32) {
        const int k = k0 + quad * 8;
        float4 a0 = *(const float4*)(A + (size_t)arow * CH + k);
        float4 a1 = *(const float4*)(A + (size_t)arow * CH + k + 4);
        bf16x8 af;
        af[0] = (__bf16)a0.x; af[1] = (__bf16)a0.y;
        af[2] = (__bf16)a0.z; af[3] = (__bf16)a0.w;
        af[4] = (__bf16)a1.x; af[5] = (__bf16)a1.y;
        af[6] = (__bf16)a1.z; af[7] = (__bf16)a1.w;
        #pragma unroll
        for (int ct = 0; ct < 8; ++ct) {
            bf16x8 bfrag = *(const bf16x8*)(Wt + (size_t)(ct * 16 + ln) * CH + k);
            acc[ct] = __builtin_amdgcn_mfma_f32_16x16x32_bf16(af, bfrag, acc[ct], 0, 0, 0);
        }
    }

    #pragma unroll
    for (int r = 0; r < 4; ++r) {
        const int row_r = rt * 16 + quad * 4 + r;
        const float dr = dinv[row_r];
        __bf16* orow = hs + (size_t)row_r * CH + ln;
        #pragma unroll
        for (int ct = 0; ct < 8; ++ct)
            orow[ct * 16] = (__bf16)(acc[ct][r] * dr);
    }
}

// ---------------------------------------------------------------------------
// conv2 GEMM (bf16 A + fused BN1-apply + relu)
// ---------------------------------------------------------------------------
__global__ __launch_bounds__(256) void gemm_bn(const __bf16* __restrict__ A,
                                               const __bf16* __restrict__ Wt,
                                               const float* __restrict__ dinv,
                                               const float* __restrict__ scale,
                                               const float* __restrict__ shift,
                                               __bf16* __restrict__ hs) {
    const int wave = threadIdx.x >> 6;
    const int rt = blockIdx.x * 4 + wave;
    if (rt >= N_NODES / 16) return;
    const int lane = threadIdx.x & 63;
    const int ln = lane & 15;
    const int quad = lane >> 4;
    const int arow = rt * 16 + ln;

    f32x4 acc[8];
    #pragma unroll
    for (int ct = 0; ct < 8; ++ct) acc[ct] = (f32x4){0.f, 0.f, 0.f, 0.f};

    #pragma unroll
    for (int k0 = 0; k0 < 128; k0 += 32) {
        const int k = k0 + quad * 8;
        bf16x8 av = *(const bf16x8*)(A + (size_t)arow * CH + k);
        bf16x8 af;
        #pragma unroll
        for (int j = 0; j < 8; ++j)
            af[j] = (__bf16)fmaxf(fmaf((float)av[j], scale[k + j], shift[k + j]), 0.f);
        #pragma unroll
        for (int ct = 0; ct < 8; ++ct) {
            bf16x8 bfrag = *(const bf16x8*)(Wt + (size_t)(ct * 16 + ln) * CH + k);
            acc[ct] = __builtin_amdgcn_mfma_f32_16x16x32_bf16(af, bfrag, acc[ct], 0, 0, 0);
        }
    }

    #pragma unroll
    for (int r = 0; r < 4; ++r) {
        const int row_r = rt * 16 + quad * 4 + r;
        const float dr = dinv[row_r];
        __bf16* orow = hs + (size_t)row_r * CH + ln;
        #pragma unroll
        for (int ct = 0; ct < 8; ++ct)
            orow[ct * 16] = (__bf16)(acc[ct][r] * dr);
    }
}

// ---------------------------------------------------------------------------
// pull-gather v2 + fused BN stats.
// Lane = eg*16+lg: eg = edge slot (4 edges per load instr), lg = channel
// group (8 ch, bf16x8 = dwordx4). 16 edges (4 KB) in flight per wave.
// Block = 4 waves x 4 sequential nodes = 16 nodes; stats held in registers
// across nodes, one LDS reduce + 256 atomics per block (1.6M total).
// ---------------------------------------------------------------------------
__global__ __launch_bounds__(256) void gather_agg(const __bf16* __restrict__ hs,
                                                  const int* __restrict__ srcs,
                                                  const int* __restrict__ rowptr,
                                                  const float* __restrict__ dinv,
                                                  __bf16* __restrict__ agg,
                                                  float* __restrict__ gpart) {
    __shared__ float red[4][256];
    const int wave = threadIdx.x >> 6;
    const int lane = threadIdx.x & 63;
    const int lg = lane & 15;                     // channels lg*8 .. lg*8+7
    const int eg = lane >> 4;                     // edge slot 0..3
    const bf16x8* hp8 = (const bf16x8*)hs;        // index: node*16 + lg

    float sstat[8], sstat2[8];
    #pragma unroll
    for (int i = 0; i < 8; ++i) { sstat[i] = 0.f; sstat2[i] = 0.f; }

    for (int it = 0; it < 4; ++it) {
        const int n = __builtin_amdgcn_readfirstlane(blockIdx.x * 16 + wave * 4 + it);
        const int beg = rowptr[n];
        const int end = rowptr[n + 1];

        bf16x8 sv = hp8[(size_t)n * 16 + lg];     // self row (broadcast load)
        float acc[8];
        #pragma unroll
        for (int i = 0; i < 8; ++i) acc[i] = (eg == 0) ? (float)sv[i] : 0.f;

        int j = beg;
        for (; j + 16 <= end; j += 16) {          // 16 edges, 4 dwordx4/lane
            int s0 = srcs[j + eg];
            int s1 = srcs[j + 4 + eg];
            int s2 = srcs[j + 8 + eg];
            int s3 = srcs[j + 12 + eg];
            bf16x8 v0 = hp8[(size_t)s0 * 16 + lg];
            bf16x8 v1 = hp8[(size_t)s1 * 16 + lg];
            bf16x8 v2 = hp8[(size_t)s2 * 16 + lg];
            bf16x8 v3 = hp8[(size_t)s3 * 16 + lg];
            #pragma unroll
            for (int i = 0; i < 8; ++i)
                acc[i] += (((float)v0[i] + (float)v1[i]) +
                           ((float)v2[i] + (float)v3[i]));
        }
        for (; j + 4 <= end; j += 4) {
            int s = srcs[j + eg];
            bf16x8 v = hp8[(size_t)s * 16 + lg];
            #pragma unroll
            for (int i = 0; i < 8; ++i) acc[i] += (float)v[i];
        }
        if (j < end) {                            // masked tail (<4 edges)
            int idx = j + eg;
            if (idx < end) {
                int s = srcs[idx];
                bf16x8 v = hp8[(size_t)s * 16 + lg];
                #pragma unroll
                for (int i = 0; i < 8; ++i) acc[i] += (float)v[i];
            }
        }

        // reduce edge slots: lanes differing in bits 4,5 hold partials
        #pragma unroll
        for (int i = 0; i < 8; ++i) {
            acc[i] += __shfl_xor(acc[i], 16, 64);
            acc[i] += __shfl_xor(acc[i], 32, 64);
        }

        const float d = dinv[n];
        bf16x8 o;
        #pragma unroll
        for (int i = 0; i < 8; ++i) {
            float ox = acc[i] * d;
            o[i] = (__bf16)ox;
            sstat[i] += ox;
            sstat2[i] += ox * ox;
        }
        if (eg == 0)
            ((bf16x8*)agg)[(size_t)n * 16 + lg] = o;
    }

    // stats: eg==0 lanes hold true per-channel accumulations
    if (eg == 0) {
        #pragma unroll
        for (int i = 0; i < 8; ++i) {
            red[wave][lg * 16 + i]     = sstat[i];
            red[wave][lg * 16 + 8 + i] = sstat2[i];
        }
    }
    __syncthreads();
    const int t = threadIdx.x;                    // slot = lg*16 + comp
    float v = red[0][t] + red[1][t] + red[2][t] + red[3][t];
    atomicAdd(&gpart[(blockIdx.x & (NREP - 1)) * 256 + t], v);
}

// ---------------------------------------------------------------------------
// reduce 64 replicas -> mu/var -> scale/shift
// slot layout: gpart[r*256 + lg*16 + i] = sum ch lg*8+i; +8 = sumsq
// ---------------------------------------------------------------------------
__global__ void bn_final(const float* __restrict__ gpart,
                         const float* __restrict__ gamma,
                         const float* __restrict__ beta,
                         float* __restrict__ scale,
                         float* __restrict__ shift) {
    int c = threadIdx.x;                          // 128 threads
    int lg = c >> 3, i = c & 7;
    float s = 0.f, ss = 0.f;
    for (int r = 0; r < NREP; ++r) {
        s  += gpart[r * 256 + lg * 16 + i];
        ss += gpart[r * 256 + lg * 16 + 8 + i];
    }
    const float invN = 1.0f / (float)N_NODES;
    float mu = s * invN;
    float var = ss * invN - mu * mu;
    float sc = gamma[c] * rsqrtf(var + BN_EPS);
    scale[c] = sc;
    shift[c] = beta[c] - mu * sc;
}

// ---------------------------------------------------------------------------
// final epilogue: out = relu(agg*scale + shift + x)   (agg bf16, out fp32)
// ---------------------------------------------------------------------------
__global__ __launch_bounds__(256) void bn_apply_res_relu(const __bf16* __restrict__ v,
                                                         const float* __restrict__ scale,
                                                         const float* __restrict__ shift,
                                                         const float* __restrict__ xin,
                                                         float* __restrict__ outv) {
    int i = blockIdx.x * 256 + threadIdx.x;       // float4 index over N*32
    int cg = i & 31;
    bf16x4 a4 = ((const bf16x4*)v)[i];
    float4 r = ((const float4*)xin)[i];
    float4 sc = ((const float4*)scale)[cg];
    float4 sh = ((const float4*)shift)[cg];
    float4 a;
    a.x = fmaxf(fmaf((float)a4[0], sc.x, sh.x) + r.x, 0.f);
    a.y = fmaxf(fmaf((float)a4[1], sc.y, sh.y) + r.y, 0.f);
    a.z = fmaxf(fmaf((float)a4[2], sc.z, sh.z) + r.z, 0.f);
    a.w = fmaxf(fmaf((float)a4[3], sc.w, sh.w) + r.w, 0.f);
    ((float4*)outv)[i] = a;
}

// ---------------------------------------------------------------------------
extern "C" void kernel_launch(void* const* d_in, const int* in_sizes, int n_in,
                              void* d_out, int out_size, void* d_ws, size_t ws_size,
                              hipStream_t stream) {
    const float* x      = (const float*)d_in[0];
    const float* W1     = (const float*)d_in[1];
    // b1/b2 cancel exactly inside BatchNorm (per-channel constant shift)
    const float* W2     = (const float*)d_in[3];
    const float* gamma2 = (const float*)d_in[5];
    const float* beta2  = (const float*)d_in[6];
    const int*   ei     = (const int*)d_in[7];    // [2, E] int32
    const int*   srcI   = ei;
    const int*   dstI   = ei + EDGES;
    float* out = (float*)d_out;

    char* ws = (char*)d_ws;
    __bf16* agg      = (__bf16*)(ws);                      // 25.6 MB
    __bf16* hs       = (__bf16*)(ws + 25600000);           // 25.6 MB
    int*    binned   = (int*)   (ws + 51200000);           // 6.4 MB
    int*    srcs     = (int*)   (ws + 57600000);           // 6.4 MB
    int*    histo_g  = (int*)   (ws + 64000000);           // 400,384 B
    int*    scanned  = (int*)   (ws + 64400512);           // (HM+1) ints
    int*    blocksum = (int*)   (ws + 64801024);           // 1,564 B
    float*  dinv     = (float*) (ws + 64802688);           // 400 KB
    int*    rowptr   = (int*)   (ws + 65202688);           // 400,004 B
    __bf16* Wt1      = (__bf16*)(ws + 65602816);           // 32 KB
    __bf16* Wt2      = (__bf16*)(ws + 65635584);           // 32 KB
    float*  gpart    = (float*) (ws + 65668352);           // 64*256*4 = 64 KB
    float*  scale1   = (float*) (ws + 65733888);           // 4 x 128 f
    float*  shift1   = scale1 + 128;
    float*  scale2   = scale1 + 256;
    float*  shift2   = scale1 + 384;

    const int ELEM4_BLOCKS = (N_NODES * 32) / 256;        // 12500
    const int GEMM_BLOCKS  = (N_NODES / 16 + 3) / 4;      // 1563
    const int GATHER_BLOCKS = N_NODES / 16;               // 6250, exact

    // ---- binning + CSR (once, reused by both convs) ----
    histo_kernel<<<CHUNKS, 256, 0, stream>>>(dstI, histo_g);
    scan1<<<SCAN_NB, 256, 0, stream>>>(histo_g, scanned, blocksum);
    scan2<<<1, 512, 0, stream>>>(blocksum);
    scan3<<<SCAN_NB, 256, 0, stream>>>(scanned, blocksum);
    place_kernel<<<CHUNKS, 256, 0, stream>>>(srcI, dstI, scanned, binned);
    bin_csr<<<BINS, 256, 0, stream>>>(binned, scanned, srcs, rowptr, dinv);
    wtrans2<<<128, 256, 0, stream>>>(W1, Wt1, W2, Wt2);

    // ---- conv1 ----
    gemm_f32<<<GEMM_BLOCKS, 256, 0, stream>>>(x, Wt1, dinv, hs);
    hipMemsetAsync(gpart, 0, NREP * 256 * sizeof(float), stream);
    gather_agg<<<GATHER_BLOCKS, 256, 0, stream>>>(hs, srcs, rowptr, dinv, agg, gpart);
    bn_final<<<1, 128, 0, stream>>>(gpart, gamma2, beta2, scale1, shift1);

    // ---- conv2 (BN1-apply + relu fused into A-fragment load) ----
    gemm_bn<<<GEMM_BLOCKS, 256, 0, stream>>>(agg, Wt2, dinv, scale1, shift1, hs);
    hipMemsetAsync(gpart, 0, NREP * 256 * sizeof(float), stream);
    gather_agg<<<GATHER_BLOCKS, 256, 0, stream>>>(hs, srcs, rowptr, dinv, agg, gpart);
    bn_final<<<1, 128, 0, stream>>>(gpart, gamma2, beta2, scale2, shift2);
    bn_apply_res_relu<<<ELEM4_BLOCKS, 256, 0, stream>>>(agg, scale2, shift2, x, out);
}

// Round 8
// 382.912 us; speedup vs baseline: 1.0967x; 1.0967x over previous
//
#include <hip/hip_runtime.h>

#define N_NODES 100000
#define EDGES   1600000
#define CH      128
#define BN_EPS  1e-5f

#define BINS     782                  // ceil(100000 / 128)
#define CHUNKS   256                  // edge chunks for binning
#define CHUNK_E  (EDGES / CHUNKS)     // 6250, exact
#define HM       (BINS * CHUNKS)      // 200192 histogram cells
#define SCAN_NB  (HM / 256)           // 782, exact
#define NREP     64                   // BN-partial replicas

typedef __attribute__((ext_vector_type(8))) __bf16 bf16x8;
typedef __attribute__((ext_vector_type(4))) __bf16 bf16x4;
typedef __attribute__((ext_vector_type(2))) __bf16 bf16x2;
typedef __attribute__((ext_vector_type(4))) float  f32x4;

// ---------------------------------------------------------------------------
// Pass 1: per-(bin, chunk) histogram.  histo_g[bin*CHUNKS + chunk]
// ---------------------------------------------------------------------------
__global__ __launch_bounds__(256) void histo_kernel(const int* __restrict__ dst,
                                                    int* __restrict__ histo_g) {
    __shared__ int h[BINS];
    int t = threadIdx.x;
    for (int b = t; b < BINS; b += 256) h[b] = 0;
    __syncthreads();
    int base = blockIdx.x * CHUNK_E;
    for (int i = t; i < CHUNK_E; i += 256)
        atomicAdd(&h[dst[base + i] >> 7], 1);
    __syncthreads();
    for (int b = t; b < BINS; b += 256)
        histo_g[b * CHUNKS + blockIdx.x] = h[b];
}

// ---------------------------------------------------------------------------
// exclusive scan over HM elements
// ---------------------------------------------------------------------------
__global__ __launch_bounds__(256) void scan1(const int* __restrict__ in,
                                             int* __restrict__ scanned,
                                             int* __restrict__ blocksum) {
    __shared__ int sh[2][256];
    int t = threadIdx.x;
    int i = blockIdx.x * 256 + t;
    int v = in[i];
    sh[0][t] = v;
    __syncthreads();
    int pp = 0;
    #pragma unroll
    for (int off = 1; off < 256; off <<= 1) {
        int val = sh[pp][t] + ((t >= off) ? sh[pp][t - off] : 0);
        sh[1 - pp][t] = val;
        pp = 1 - pp;
        __syncthreads();
    }
    int incl = sh[pp][t];
    scanned[i] = incl - v;
    if (t == 255) blocksum[blockIdx.x] = incl;
}

__global__ __launch_bounds__(1024) void scan2(int* __restrict__ blocksum) {
    __shared__ int sh[2][1024];
    int t = threadIdx.x;
    int v = (t < SCAN_NB) ? blocksum[t] : 0;
    sh[0][t] = v;
    __syncthreads();
    int pp = 0;
    #pragma unroll
    for (int off = 1; off < 1024; off <<= 1) {
        int val = sh[pp][t] + ((t >= off) ? sh[pp][t - off] : 0);
        sh[1 - pp][t] = val;
        pp = 1 - pp;
        __syncthreads();
    }
    if (t < SCAN_NB) blocksum[t] = sh[pp][t] - v;
}

__global__ __launch_bounds__(256) void scan3(int* __restrict__ scanned,
                                             const int* __restrict__ blocksum) {
    int i = blockIdx.x * 256 + threadIdx.x;
    scanned[i] += blocksum[blockIdx.x];
    if (i == HM - 1) scanned[HM] = EDGES;
}

// ---------------------------------------------------------------------------
// Pass 2: placement.  binned[pos] = (src << 7) | (dst & 127)
// ---------------------------------------------------------------------------
__global__ __launch_bounds__(256) void place_kernel(const int* __restrict__ src,
                                                    const int* __restrict__ dst,
                                                    const int* __restrict__ scanned,
                                                    int* __restrict__ binned) {
    __shared__ int cur[BINS];
    int t = threadIdx.x;
    for (int b = t; b < BINS; b += 256)
        cur[b] = scanned[b * CHUNKS + blockIdx.x];
    __syncthreads();
    int base = blockIdx.x * CHUNK_E;
    for (int i = t; i < CHUNK_E; i += 256) {
        int d = dst[base + i];
        int s = src[base + i];
        int pos = atomicAdd(&cur[d >> 7], 1);
        binned[pos] = (s << 7) | (d & 127);
    }
}

// ---------------------------------------------------------------------------
// Pass 3: per-bin counting sort -> full CSR (srcs sorted by dst), rowptr, dinv.
// ---------------------------------------------------------------------------
__global__ __launch_bounds__(256) void bin_csr(const int* __restrict__ binned,
                                               const int* __restrict__ scanned,
                                               int* __restrict__ srcs,
                                               int* __restrict__ rowptr,
                                               float* __restrict__ dinv) {
    __shared__ int cnt[128];
    __shared__ int sc[2][128];
    __shared__ int base[128];
    __shared__ int cur[128];
    const int t = threadIdx.x;
    const int bin = blockIdx.x;
    if (t < 128) { cnt[t] = 0; cur[t] = 0; }
    __syncthreads();
    const int beg = scanned[bin * CHUNKS];
    const int end = scanned[bin * CHUNKS + CHUNKS];
    for (int e = beg + t; e < end; e += 256)
        atomicAdd(&cnt[binned[e] & 127], 1);
    __syncthreads();
    if (t < 128) sc[0][t] = cnt[t];
    __syncthreads();
    int pp = 0;
    #pragma unroll
    for (int off = 1; off < 128; off <<= 1) {
        if (t < 128) sc[1 - pp][t] = sc[pp][t] + ((t >= off) ? sc[pp][t - off] : 0);
        pp = 1 - pp;
        __syncthreads();
    }
    if (t < 128) {
        base[t] = beg + sc[pp][t] - cnt[t];
        int n = (bin << 7) + t;
        if (n < N_NODES) {
            rowptr[n] = base[t];
            dinv[n] = rsqrtf((float)cnt[t] + 1.0f);
        }
    }
    if (bin == 0 && t == 0) rowptr[N_NODES] = EDGES;
    __syncthreads();
    for (int e = beg + t; e < end; e += 256) {
        int p = binned[e];
        int dl = p & 127;
        int pos = base[dl] + atomicAdd(&cur[dl], 1);
        srcs[pos] = p >> 7;
    }
}

// ---------------------------------------------------------------------------
// W transpose + bf16 convert for BOTH weights: Wt[n][k] = bf16(W[k][n])
// ---------------------------------------------------------------------------
__global__ __launch_bounds__(256) void wtrans2(const float* __restrict__ W1,
                                               __bf16* __restrict__ Wt1,
                                               const float* __restrict__ W2,
                                               __bf16* __restrict__ Wt2) {
    int b = blockIdx.x;
    const float* W = (b < 64) ? W1 : W2;
    __bf16* Wt = (b < 64) ? Wt1 : Wt2;
    int idx = (b & 63) * 256 + threadIdx.x;
    int n = idx >> 7, k = idx & 127;
    Wt[idx] = (__bf16)W[k * 128 + n];
}

// ---------------------------------------------------------------------------
// conv1 GEMM (fp32 A): hs[n][c] = bf16( dinv[n] * sum_k A[n][k] * W[k][c] )
// ---------------------------------------------------------------------------
__global__ __launch_bounds__(256) void gemm_f32(const float* __restrict__ A,
                                                const __bf16* __restrict__ Wt,
                                                const float* __restrict__ dinv,
                                                __bf16* __restrict__ hs) {
    const int wave = threadIdx.x >> 6;
    const int rt = blockIdx.x * 4 + wave;
    if (rt >= N_NODES / 16) return;
    const int lane = threadIdx.x & 63;
    const int ln = lane & 15;
    const int quad = lane >> 4;
    const int arow = rt * 16 + ln;

    f32x4 acc[8];
    #pragma unroll
    for (int ct = 0; ct < 8; ++ct) acc[ct] = (f32x4){0.f, 0.f, 0.f, 0.f};

    #pragma unroll
    for (int k0 = 0; k0 < 128; k0 += 32) {
        const int k = k0 + quad * 8;
        float4 a0 = *(const float4*)(A + (size_t)arow * CH + k);
        float4 a1 = *(const float4*)(A + (size_t)arow * CH + k + 4);
        bf16x8 af;
        af[0] = (__bf16)a0.x; af[1] = (__bf16)a0.y;
        af[2] = (__bf16)a0.z; af[3] = (__bf16)a0.w;
        af[4] = (__bf16)a1.x; af[5] = (__bf16)a1.y;
        af[6] = (__bf16)a1.z; af[7] = (__bf16)a1.w;
        #pragma unroll
        for (int ct = 0; ct < 8; ++ct) {
            bf16x8 bfrag = *(const bf16x8*)(Wt + (size_t)(ct * 16 + ln) * CH + k);
            acc[ct] = __builtin_amdgcn_mfma_f32_16x16x32_bf16(af, bfrag, acc[ct], 0, 0, 0);
        }
    }

    #pragma unroll
    for (int r = 0; r < 4; ++r) {
        const int row_r = rt * 16 + quad * 4 + r;
        const float dr = dinv[row_r];
        __bf16* orow = hs + (size_t)row_r * CH + ln;
        #pragma unroll
        for (int ct = 0; ct < 8; ++ct)
            orow[ct * 16] = (__bf16)(acc[ct][r] * dr);
    }
}

// ---------------------------------------------------------------------------
// conv2 GEMM (bf16 A + fused BN1-apply + relu)
// ---------------------------------------------------------------------------
__global__ __launch_bounds__(256) void gemm_bn(const __bf16* __restrict__ A,
                                               const __bf16* __restrict__ Wt,
                                               const float* __restrict__ dinv,
                                               const float* __restrict__ scale,
                                               const float* __restrict__ shift,
                                               __bf16* __restrict__ hs) {
    const int wave = threadIdx.x >> 6;
    const int rt = blockIdx.x * 4 + wave;
    if (rt >= N_NODES / 16) return;
    const int lane = threadIdx.x & 63;
    const int ln = lane & 15;
    const int quad = lane >> 4;
    const int arow = rt * 16 + ln;

    f32x4 acc[8];
    #pragma unroll
    for (int ct = 0; ct < 8; ++ct) acc[ct] = (f32x4){0.f, 0.f, 0.f, 0.f};

    #pragma unroll
    for (int k0 = 0; k0 < 128; k0 += 32) {
        const int k = k0 + quad * 8;
        bf16x8 av = *(const bf16x8*)(A + (size_t)arow * CH + k);
        bf16x8 af;
        #pragma unroll
        for (int j = 0; j < 8; ++j)
            af[j] = (__bf16)fmaxf(fmaf((float)av[j], scale[k + j], shift[k + j]), 0.f);
        #pragma unroll
        for (int ct = 0; ct < 8; ++ct) {
            bf16x8 bfrag = *(const bf16x8*)(Wt + (size_t)(ct * 16 + ln) * CH + k);
            acc[ct] = __builtin_amdgcn_mfma_f32_16x16x32_bf16(af, bfrag, acc[ct], 0, 0, 0);
        }
    }

    #pragma unroll
    for (int r = 0; r < 4; ++r) {
        const int row_r = rt * 16 + quad * 4 + r;
        const float dr = dinv[row_r];
        __bf16* orow = hs + (size_t)row_r * CH + ln;
        #pragma unroll
        for (int ct = 0; ct < 8; ++ct)
            orow[ct * 16] = (__bf16)(acc[ct][r] * dr);
    }
}

// ---------------------------------------------------------------------------
// pull-gather (R6-v1 structure) + fused BN stats.
// One wave per node, 2 sequential nodes per wave (adjacent edge segments),
// lane = channel pair (bf16x2 dword loads -> 256B coalesced row reads),
// wave-uniform node index -> scalar rowptr/srcs loads, 8-deep unroll.
// Block = 4 waves x 2 nodes = 8 nodes; 12500 blocks; stats kept in regs
// across both nodes -> one LDS reduce + 256 atomics per block (3.2M total).
// ---------------------------------------------------------------------------
__global__ __launch_bounds__(256) void gather_agg(const __bf16* __restrict__ hs,
                                                  const int* __restrict__ srcs,
                                                  const int* __restrict__ rowptr,
                                                  const float* __restrict__ dinv,
                                                  __bf16* __restrict__ agg,
                                                  float* __restrict__ gpart) {
    __shared__ float red[4][64][4];
    const int wave = threadIdx.x >> 6;
    const int c2 = threadIdx.x & 63;
    const bf16x2* hp = (const bf16x2*)hs;

    float s0 = 0.f, ss0 = 0.f, s1 = 0.f, ss1 = 0.f;

    #pragma unroll
    for (int it = 0; it < 2; ++it) {
        const int n = __builtin_amdgcn_readfirstlane(blockIdx.x * 8 + wave * 2 + it);
        const int beg = rowptr[n];
        const int end = rowptr[n + 1];
        bf16x2 sv = hp[(size_t)n * 64 + c2];
        float ax = (float)sv[0], ay = (float)sv[1];
        int j = beg;
        for (; j + 8 <= end; j += 8) {
            int e0 = srcs[j + 0], e1 = srcs[j + 1], e2 = srcs[j + 2], e3 = srcs[j + 3];
            int e4 = srcs[j + 4], e5 = srcs[j + 5], e6 = srcs[j + 6], e7 = srcs[j + 7];
            bf16x2 v0 = hp[(size_t)e0 * 64 + c2];
            bf16x2 v1 = hp[(size_t)e1 * 64 + c2];
            bf16x2 v2 = hp[(size_t)e2 * 64 + c2];
            bf16x2 v3 = hp[(size_t)e3 * 64 + c2];
            bf16x2 v4 = hp[(size_t)e4 * 64 + c2];
            bf16x2 v5 = hp[(size_t)e5 * 64 + c2];
            bf16x2 v6 = hp[(size_t)e6 * 64 + c2];
            bf16x2 v7 = hp[(size_t)e7 * 64 + c2];
            ax += (((float)v0[0] + (float)v1[0]) + ((float)v2[0] + (float)v3[0]))
                + (((float)v4[0] + (float)v5[0]) + ((float)v6[0] + (float)v7[0]));
            ay += (((float)v0[1] + (float)v1[1]) + ((float)v2[1] + (float)v3[1]))
                + (((float)v4[1] + (float)v5[1]) + ((float)v6[1] + (float)v7[1]));
        }
        for (; j < end; ++j) {
            bf16x2 v = hp[(size_t)srcs[j] * 64 + c2];
            ax += (float)v[0];
            ay += (float)v[1];
        }
        float d = dinv[n];
        float ox = ax * d, oy = ay * d;
        bf16x2 o; o[0] = (__bf16)ox; o[1] = (__bf16)oy;
        ((bf16x2*)agg)[(size_t)n * 64 + c2] = o;
        s0 += ox; ss0 += ox * ox;
        s1 += oy; ss1 += oy * oy;
    }

    // BN partials: red[wave][c2] = {sum_even, sumsq_even, sum_odd, sumsq_odd}
    f32x4 rv; rv[0] = s0; rv[1] = ss0; rv[2] = s1; rv[3] = ss1;
    *(f32x4*)red[wave][c2] = rv;
    __syncthreads();
    const int t = threadIdx.x;                    // slot = (c2'<<2)|comp = t
    float v = red[0][t >> 2][t & 3] + red[1][t >> 2][t & 3] +
              red[2][t >> 2][t & 3] + red[3][t >> 2][t & 3];
    atomicAdd(&gpart[(blockIdx.x & (NREP - 1)) * 256 + t], v);
}

// ---------------------------------------------------------------------------
// reduce 64 replicas -> mu/var -> scale/shift
// slot layout: gpart[r*256 + c2*4 + {0,1,2,3}] = {s_even, ss_even, s_odd, ss_odd}
// ---------------------------------------------------------------------------
__global__ void bn_final(const float* __restrict__ gpart,
                         const float* __restrict__ gamma,
                         const float* __restrict__ beta,
                         float* __restrict__ scale,
                         float* __restrict__ shift) {
    int c = threadIdx.x;                          // 128 threads
    int c2 = c >> 1, odd = c & 1;
    float s = 0.f, ss = 0.f;
    for (int r = 0; r < NREP; ++r) {
        s  += gpart[r * 256 + c2 * 4 + 2 * odd];
        ss += gpart[r * 256 + c2 * 4 + 2 * odd + 1];
    }
    const float invN = 1.0f / (float)N_NODES;
    float mu = s * invN;
    float var = ss * invN - mu * mu;
    float sc = gamma[c] * rsqrtf(var + BN_EPS);
    scale[c] = sc;
    shift[c] = beta[c] - mu * sc;
}

// ---------------------------------------------------------------------------
// final epilogue: out = relu(agg*scale + shift + x)   (agg bf16, out fp32)
// ---------------------------------------------------------------------------
__global__ __launch_bounds__(256) void bn_apply_res_relu(const __bf16* __restrict__ v,
                                                         const float* __restrict__ scale,
                                                         const float* __restrict__ shift,
                                                         const float* __restrict__ xin,
                                                         float* __restrict__ outv) {
    int i = blockIdx.x * 256 + threadIdx.x;       // float4 index over N*32
    int cg = i & 31;
    bf16x4 a4 = ((const bf16x4*)v)[i];
    float4 r = ((const float4*)xin)[i];
    float4 sc = ((const float4*)scale)[cg];
    float4 sh = ((const float4*)shift)[cg];
    float4 a;
    a.x = fmaxf(fmaf((float)a4[0], sc.x, sh.x) + r.x, 0.f);
    a.y = fmaxf(fmaf((float)a4[1], sc.y, sh.y) + r.y, 0.f);
    a.z = fmaxf(fmaf((float)a4[2], sc.z, sh.z) + r.z, 0.f);
    a.w = fmaxf(fmaf((float)a4[3], sc.w, sh.w) + r.w, 0.f);
    ((float4*)outv)[i] = a;
}

// ---------------------------------------------------------------------------
extern "C" void kernel_launch(void* const* d_in, const int* in_sizes, int n_in,
                              void* d_out, int out_size, void* d_ws, size_t ws_size,
                              hipStream_t stream) {
    const float* x      = (const float*)d_in[0];
    const float* W1     = (const float*)d_in[1];
    // b1/b2 cancel exactly inside BatchNorm (per-channel constant shift)
    const float* W2     = (const float*)d_in[3];
    const float* gamma2 = (const float*)d_in[5];
    const float* beta2  = (const float*)d_in[6];
    const int*   ei     = (const int*)d_in[7];    // [2, E] int32
    const int*   srcI   = ei;
    const int*   dstI   = ei + EDGES;
    float* out = (float*)d_out;

    char* ws = (char*)d_ws;
    __bf16* agg      = (__bf16*)(ws);                      // 25.6 MB
    __bf16* hs       = (__bf16*)(ws + 25600000);           // 25.6 MB
    int*    binned   = (int*)   (ws + 51200000);           // 6.4 MB
    int*    srcs     = (int*)   (ws + 57600000);           // 6.4 MB
    int*    histo_g  = (int*)   (ws + 64000000);           // 800,768 B
    int*    scanned  = (int*)   (ws + 64801024);           // (HM+1) ints = 800,772 B
    int*    blocksum = (int*)   (ws + 65602048);           // 3,128 B
    float*  dinv     = (float*) (ws + 65605632);           // 400 KB
    int*    rowptr   = (int*)   (ws + 66005632);           // 400,004 B
    __bf16* Wt1      = (__bf16*)(ws + 66405888);           // 32 KB
    __bf16* Wt2      = (__bf16*)(ws + 66438656);           // 32 KB
    float*  gpart    = (float*) (ws + 66471424);           // 64*256*4 = 64 KB
    float*  scale1   = (float*) (ws + 66536960);           // 4 x 128 f
    float*  shift1   = scale1 + 128;
    float*  scale2   = scale1 + 256;
    float*  shift2   = scale1 + 384;

    const int ELEM4_BLOCKS  = (N_NODES * 32) / 256;       // 12500
    const int GEMM_BLOCKS   = (N_NODES / 16 + 3) / 4;     // 1563
    const int GATHER_BLOCKS = N_NODES / 8;                // 12500, exact

    // ---- binning + CSR (once, reused by both convs) ----
    histo_kernel<<<CHUNKS, 256, 0, stream>>>(dstI, histo_g);
    scan1<<<SCAN_NB, 256, 0, stream>>>(histo_g, scanned, blocksum);
    scan2<<<1, 1024, 0, stream>>>(blocksum);
    scan3<<<SCAN_NB, 256, 0, stream>>>(scanned, blocksum);
    place_kernel<<<CHUNKS, 256, 0, stream>>>(srcI, dstI, scanned, binned);
    bin_csr<<<BINS, 256, 0, stream>>>(binned, scanned, srcs, rowptr, dinv);
    wtrans2<<<128, 256, 0, stream>>>(W1, Wt1, W2, Wt2);

    // ---- conv1 ----
    gemm_f32<<<GEMM_BLOCKS, 256, 0, stream>>>(x, Wt1, dinv, hs);
    hipMemsetAsync(gpart, 0, NREP * 256 * sizeof(float), stream);
    gather_agg<<<GATHER_BLOCKS, 256, 0, stream>>>(hs, srcs, rowptr, dinv, agg, gpart);
    bn_final<<<1, 128, 0, stream>>>(gpart, gamma2, beta2, scale1, shift1);

    // ---- conv2 (BN1-apply + relu fused into A-fragment load) ----
    gemm_bn<<<GEMM_BLOCKS, 256, 0, stream>>>(agg, Wt2, dinv, scale1, shift1, hs);
    hipMemsetAsync(gpart, 0, NREP * 256 * sizeof(float), stream);
    gather_agg<<<GATHER_BLOCKS, 256, 0, stream>>>(hs, srcs, rowptr, dinv, agg, gpart);
    bn_final<<<1, 128, 0, stream>>>(gpart, gamma2, beta2, scale2, shift2);
    bn_apply_res_relu<<<ELEM4_BLOCKS, 256, 0, stream>>>(agg, scale2, shift2, x, out);
}